// Round 1
// baseline (7568.425 us; speedup 1.0000x reference)
//
#include <hip/hip_runtime.h>
#include <math.h>

#define BB 256
#define TT 128
#define NN 512
#define HH 512
#define G3 1536
#define CST 3072   // C row stride: [xi gates 0..1535 | h gates 1536..3071]

__global__ void zero_kernel(float* p, int n) {
    int i = blockIdx.x * blockDim.x + threadIdx.x;
    if (i < n) p[i] = 0.f;
}

// C[256][3072]: cols [0,1536) = X @ Wih^T + bih ; cols [1536,3072) = Hs @ Whh^T + bhh
// X row stride = xStride (layer0: x_t rows are T*N apart; layer1: h0 rows are 512 apart)
__global__ __launch_bounds__(256) void gru_gemm(
    const float* __restrict__ X, int xStride,
    const float* __restrict__ Hs,
    const float* __restrict__ Wih, const float* __restrict__ Whh,
    const float* __restrict__ bih, const float* __restrict__ bhh,
    float* __restrict__ C) {
    __shared__ __align__(16) float As[16][68];
    __shared__ __align__(16) float Bs[16][68];
    const int tid = threadIdx.x;
    const int m0 = blockIdx.x * 64;
    const int g0 = blockIdx.y * 64;

    const float* A; int aStr; const float* W; const float* bias;
    if (g0 < G3) { A = X;  aStr = xStride; W = Wih + g0 * 512;        bias = bih + g0; }
    else         { A = Hs; aStr = HH;      W = Whh + (g0 - G3) * 512; bias = bhh + (g0 - G3); }

    const int lr = tid >> 2;          // 0..63 tile row
    const int lc = (tid & 3) * 4;     // 0,4,8,12 k offset
    const int tm = (tid >> 4) * 4;    // 0..60 output row base
    const int tn = (tid & 15) * 4;    // 0..60 output col base

    float acc[4][4] = {};

    for (int k0 = 0; k0 < 512; k0 += 16) {
        float4 av = *(const float4*)(A + (size_t)(m0 + lr) * aStr + k0 + lc);
        float4 wv = *(const float4*)(W + lr * 512 + k0 + lc);
        As[lc + 0][lr] = av.x; As[lc + 1][lr] = av.y; As[lc + 2][lr] = av.z; As[lc + 3][lr] = av.w;
        Bs[lc + 0][lr] = wv.x; Bs[lc + 1][lr] = wv.y; Bs[lc + 2][lr] = wv.z; Bs[lc + 3][lr] = wv.w;
        __syncthreads();
#pragma unroll
        for (int kk = 0; kk < 16; ++kk) {
            float4 a = *(const float4*)&As[kk][tm];
            float4 b = *(const float4*)&Bs[kk][tn];
            float ar[4] = {a.x, a.y, a.z, a.w};
            float br[4] = {b.x, b.y, b.z, b.w};
#pragma unroll
            for (int i = 0; i < 4; ++i)
#pragma unroll
                for (int j = 0; j < 4; ++j)
                    acc[i][j] += ar[i] * br[j];
        }
        __syncthreads();
    }

    float4 bv = *(const float4*)(bias + tn);
    float bb[4] = {bv.x, bv.y, bv.z, bv.w};
#pragma unroll
    for (int i = 0; i < 4; ++i) {
        float4 o;
        o.x = acc[i][0] + bb[0];
        o.y = acc[i][1] + bb[1];
        o.z = acc[i][2] + bb[2];
        o.w = acc[i][3] + bb[3];
        *(float4*)(C + (size_t)(m0 + tm + i) * CST + g0 + tn) = o;
    }
}

// GRU gate update: h = (1-z)*n + z*h from C = [xr xz xn | hr hz hn]
__global__ void gru_update(const float* __restrict__ C, float* __restrict__ h) {
    int i = blockIdx.x * 256 + threadIdx.x;   // < 256*512
    int b = i >> 9, j = i & 511;
    const float* cr = C + (size_t)b * CST;
    float xr = cr[j], xz = cr[512 + j], xn = cr[1024 + j];
    float hr = cr[1536 + j], hz = cr[2048 + j], hn = cr[2560 + j];
    float r = 1.f / (1.f + expf(-(xr + hr)));
    float z = 1.f / (1.f + expf(-(xz + hz)));
    float n = tanhf(xn + r * hn);
    h[i] = (1.f - z) * n + z * h[i];
}

__device__ __forceinline__ float blockReduceSum(float v, float* tmp) {
    __syncthreads();
#pragma unroll
    for (int o = 32; o; o >>= 1) v += __shfl_down(v, o);
    if ((threadIdx.x & 63) == 0) tmp[threadIdx.x >> 6] = v;
    __syncthreads();
    if (threadIdx.x == 0) tmp[4] = tmp[0] + tmp[1] + tmp[2] + tmp[3];
    __syncthreads();
    return tmp[4];
}

__device__ __forceinline__ float blockReduceMax(float v, float* tmp) {
    __syncthreads();
#pragma unroll
    for (int o = 32; o; o >>= 1) v = fmaxf(v, __shfl_down(v, o));
    if ((threadIdx.x & 63) == 0) tmp[threadIdx.x >> 6] = v;
    __syncthreads();
    if (threadIdx.x == 0) tmp[4] = fmaxf(fmaxf(tmp[0], tmp[1]), fmaxf(tmp[2], tmp[3]));
    __syncthreads();
    return tmp[4];
}

// Per-batch-row: logit = h1 @ fcw^T + fcb; silu; softmax; 32-iter rebalance.
__global__ __launch_bounds__(256) void head_kernel(
    const float* __restrict__ h1, const float* __restrict__ fcw,
    const float* __restrict__ fcb, float* __restrict__ out) {
    __shared__ __align__(16) float hrow[512];
    __shared__ float wv[512];
    __shared__ float ov[512];
    __shared__ float tmp[8];
    const int b = blockIdx.x, tid = threadIdx.x;
    hrow[tid]       = h1[(size_t)b * 512 + tid];
    hrow[tid + 256] = h1[(size_t)b * 512 + 256 + tid];
    __syncthreads();

    float s[2];
#pragma unroll
    for (int q = 0; q < 2; ++q) {
        int n = tid + q * 256;
        const float* wr = fcw + (size_t)n * 512;
        float acc = 0.f;
        for (int k = 0; k < 512; k += 4) {
            float4 wq = *(const float4*)(wr + k);
            acc += wq.x * hrow[k] + wq.y * hrow[k + 1] + wq.z * hrow[k + 2] + wq.w * hrow[k + 3];
        }
        float l = acc + fcb[n];
        s[q] = l / (1.f + expf(-l));   // silu
    }

    // softmax over 512
    float mx = blockReduceMax(fmaxf(s[0], s[1]), tmp);
    float e0 = expf(s[0] - mx), e1 = expf(s[1] - mx);
    float sum = blockReduceSum(e0 + e1, tmp);
    float w0 = e0 / sum, w1 = e1 / sum;

    // rebalance init: old = w, wc = clip(w, 0, 0.1)
    ov[tid] = w0;       ov[tid + 256] = w1;
    wv[tid]       = fminf(fmaxf(w0, 0.f), 0.1f);
    wv[tid + 256] = fminf(fmaxf(w1, 0.f), 0.1f);
    __syncthreads();

    for (int it = 0; it < 32; ++it) {
        float wc0 = wv[tid], wc1 = wv[tid + 256];
        float o0 = ov[tid], o1 = ov[tid + 256];
        float leftover = blockReduceSum((o0 - wc0) + (o1 - wc1), tmp);
        float n0 = (wc0 != 0.1f) ? wc0 : 0.f;
        float n1 = (wc1 != 0.1f) ? wc1 : 0.f;
        float denom = blockReduceSum(n0 + n1, tmp);
        float w20 = wc0 + leftover * n0 / denom;
        float w21 = wc1 + leftover * n1 / denom;
        float fl = ((w20 > 0.1f) || (w21 > 0.1f)) ? 1.f : 0.f;
        bool again = blockReduceSum(fl, tmp) > 0.f;
        __syncthreads();
        ov[tid] = w20; ov[tid + 256] = w21;
        wv[tid]       = again ? fminf(fmaxf(w20, 0.f), 0.1f) : w20;
        wv[tid + 256] = again ? fminf(fmaxf(w21, 0.f), 0.1f) : w21;
        __syncthreads();
        if (!again) break;
    }

    out[(size_t)b * 512 + tid]       = wv[tid];
    out[(size_t)b * 512 + 256 + tid] = wv[tid + 256];
}

extern "C" void kernel_launch(void* const* d_in, const int* in_sizes, int n_in,
                              void* d_out, int out_size, void* d_ws, size_t ws_size,
                              hipStream_t stream) {
    const float* x    = (const float*)d_in[0];
    const float* Wih0 = (const float*)d_in[1];
    const float* Whh0 = (const float*)d_in[2];
    const float* bih0 = (const float*)d_in[3];
    const float* bhh0 = (const float*)d_in[4];
    const float* Wih1 = (const float*)d_in[5];
    const float* Whh1 = (const float*)d_in[6];
    const float* bih1 = (const float*)d_in[7];
    const float* bhh1 = (const float*)d_in[8];
    const float* fcw  = (const float*)d_in[9];
    const float* fcb  = (const float*)d_in[10];
    float* out = (float*)d_out;

    float* h0 = (float*)d_ws;       // 256*512
    float* h1 = h0 + BB * HH;       // 256*512
    float* C  = h1 + BB * HH;       // 256*3072

    zero_kernel<<<(2 * BB * HH + 255) / 256, 256, 0, stream>>>(h0, 2 * BB * HH);

    dim3 gg(4, 48);
    for (int t = 0; t < TT; ++t) {
        gru_gemm<<<gg, 256, 0, stream>>>(x + (size_t)t * NN, TT * NN, h0,
                                         Wih0, Whh0, bih0, bhh0, C);
        gru_update<<<(BB * HH) / 256, 256, 0, stream>>>(C, h0);
        gru_gemm<<<gg, 256, 0, stream>>>(h0, HH, h1,
                                         Wih1, Whh1, bih1, bhh1, C);
        gru_update<<<(BB * HH) / 256, 256, 0, stream>>>(C, h1);
    }
    head_kernel<<<BB, 256, 0, stream>>>(h1, fcw, fcb, out);
}

// Round 2
// 5545.369 us; speedup vs baseline: 1.3648x; 1.3648x over previous
//
#include <hip/hip_runtime.h>
#include <math.h>

#define BB 256
#define TT 128
#define NN 512
#define HH 512
#define G3 1536
#define SLAB (HH * BB)     // 131072 floats: one [512][256] transposed-state slab
#define XSLAB (G3 * BB)    // 393216 floats: one [1536][256] xi slab

__global__ void zero_kernel(float* p, int n) {
    int i = blockIdx.x * blockDim.x + threadIdx.x;
    if (i < n) p[i] = 0.f;
}

// Transpose a chunk of x: x[b][t0+t][k] -> xT[t][k][b]
__global__ __launch_bounds__(256) void x_transpose(
    const float* __restrict__ x, int t0, float* __restrict__ xT) {
    __shared__ float tb[64][65];
    const int tid = threadIdx.x;
    const int k0 = blockIdx.x * 64;
    const int b0 = blockIdx.y * 64;
    const int t  = blockIdx.z;
    const float* src = x + (size_t)(t0 + t) * NN;
#pragma unroll
    for (int i = 0; i < 4; ++i) {
        int r = (tid >> 4) + 16 * i;      // b row
        int c = (tid & 15) * 4;           // k col
        float4 v = *(const float4*)(src + (size_t)(b0 + r) * (TT * NN) + k0 + c);
        tb[c + 0][r] = v.x; tb[c + 1][r] = v.y; tb[c + 2][r] = v.z; tb[c + 3][r] = v.w;
    }
    __syncthreads();
    float* dst = xT + (size_t)t * SLAB + (size_t)k0 * 256 + b0;
#pragma unroll
    for (int i = 0; i < 4; ++i) {
        int r = (tid >> 4) + 16 * i;      // k row
        int c = (tid & 15) * 4;           // b col
        float4 v;
        v.x = tb[r][c]; v.y = tb[r][c + 1]; v.z = tb[r][c + 2]; v.w = tb[r][c + 3];
        *(float4*)(dst + (size_t)r * 256 + c) = v;
    }
}

// out[t][g][b] = sum_k W[g][k] * BT[t][k][b] + bias[g]
// 128x64 tile, 256 threads, 8x4 per thread.
__global__ __launch_bounds__(256) void xi_gemm(
    const float* __restrict__ W, const float* __restrict__ bias,
    const float* __restrict__ BT, float* __restrict__ out) {
    __shared__ __align__(16) float As[16][132];
    __shared__ __align__(16) float Bs[16][68];
    const int tid = threadIdx.x;
    const int m0 = blockIdx.x * 128;        // g tile
    const int n0 = blockIdx.y * 64;         // n = t*256 + b
    const int t_local = n0 >> 8;
    const int b0 = n0 & 255;
    const float* Bb = BT + (size_t)t_local * SLAB;

    float acc[8][4] = {};
    for (int k0 = 0; k0 < 512; k0 += 16) {
        {   // stage A: W rows
            int r = tid >> 1, kq = (tid & 1) * 8;
            const float* ap = W + (size_t)(m0 + r) * 512 + k0 + kq;
            float4 v1 = *(const float4*)ap;
            float4 v2 = *(const float4*)(ap + 4);
            As[kq + 0][r] = v1.x; As[kq + 1][r] = v1.y; As[kq + 2][r] = v1.z; As[kq + 3][r] = v1.w;
            As[kq + 4][r] = v2.x; As[kq + 5][r] = v2.y; As[kq + 6][r] = v2.z; As[kq + 7][r] = v2.w;
        }
        {   // stage B: BT[k][b], contiguous in b
            int kk = tid >> 4, nq = (tid & 15) * 4;
            *(float4*)&Bs[kk][nq] = *(const float4*)(Bb + (size_t)(k0 + kk) * 256 + b0 + nq);
        }
        __syncthreads();
#pragma unroll
        for (int kk = 0; kk < 16; ++kk) {
            float a[8], bv[4];
            *(float4*)&a[0] = *(const float4*)&As[kk][(tid & 15) * 8];
            *(float4*)&a[4] = *(const float4*)&As[kk][(tid & 15) * 8 + 4];
            *(float4*)&bv[0] = *(const float4*)&Bs[kk][(tid >> 4) * 4];
#pragma unroll
            for (int i = 0; i < 8; ++i)
#pragma unroll
                for (int j = 0; j < 4; ++j)
                    acc[i][j] += a[i] * bv[j];
        }
        __syncthreads();
    }
    const int mrow = (tid & 15) * 8;
    const int ncol = (tid >> 4) * 4;
    float* op = out + (size_t)t_local * XSLAB + (size_t)(m0 + mrow) * 256 + b0 + ncol;
#pragma unroll
    for (int i = 0; i < 8; ++i) {
        float bsv = bias[m0 + mrow + i];
        float4 o;
        o.x = acc[i][0] + bsv; o.y = acc[i][1] + bsv;
        o.z = acc[i][2] + bsv; o.w = acc[i][3] + bsv;
        *(float4*)(op + (size_t)i * 256) = o;
    }
}

// Fused recurrent step: gh = h@Whh^T + bhh (SGPR-weight GEMM), gates, h-update.
// 256 blocks (2 j-cols each) x 256 threads. lane=b-pair, wave-pair splits K.
__global__ __launch_bounds__(256) void rec_step(
    const float* __restrict__ hTprev,   // [512][256]
    const float* __restrict__ xiT,      // [1536][256] for this t
    const float* __restrict__ Whh,      // [1536][512]
    const float* __restrict__ bhh,      // [1536]
    float* __restrict__ hTnext) {       // [512][256]
    __shared__ float2 red[6 * 128];
    const int tid = threadIdx.x;
    const int b2 = tid & 127;                 // b-pair: b = 2*b2, 2*b2+1
    const int kh = tid >> 7;                  // k-half
    const int khu = __builtin_amdgcn_readfirstlane(kh);  // wave-uniform -> s_load path
    const int j0 = blockIdx.x * 2;

    const float* w0 = Whh + (size_t)j0 * 512 + khu * 256;           // r, j0
    const float* w1 = Whh + (size_t)(j0 + 1) * 512 + khu * 256;     // r, j0+1
    const float* w2 = Whh + (size_t)(512 + j0) * 512 + khu * 256;   // z, j0
    const float* w3 = Whh + (size_t)(513 + j0) * 512 + khu * 256;   // z, j0+1
    const float* w4 = Whh + (size_t)(1024 + j0) * 512 + khu * 256;  // n, j0
    const float* w5 = Whh + (size_t)(1025 + j0) * 512 + khu * 256;  // n, j0+1
    const float2* hp = (const float2*)hTprev + (size_t)khu * 256 * 128 + b2;

    float2 ar0 = {0.f, 0.f}, ar1 = ar0, az0 = ar0, az1 = ar0, an0 = ar0, an1 = ar0;
#pragma unroll 8
    for (int k = 0; k < 256; ++k) {
        float2 hv = hp[(size_t)k * 128];
        float q0 = w0[k], q1 = w1[k], q2 = w2[k], q3 = w3[k], q4 = w4[k], q5 = w5[k];
        ar0.x += q0 * hv.x; ar0.y += q0 * hv.y;
        ar1.x += q1 * hv.x; ar1.y += q1 * hv.y;
        az0.x += q2 * hv.x; az0.y += q2 * hv.y;
        az1.x += q3 * hv.x; az1.y += q3 * hv.y;
        an0.x += q4 * hv.x; an0.y += q4 * hv.y;
        an1.x += q5 * hv.x; an1.y += q5 * hv.y;
    }
    if (kh) {
        red[0 * 128 + b2] = ar0; red[1 * 128 + b2] = ar1;
        red[2 * 128 + b2] = az0; red[3 * 128 + b2] = az1;
        red[4 * 128 + b2] = an0; red[5 * 128 + b2] = an1;
    }
    __syncthreads();
    if (!kh) {
        float2 t;
        t = red[0 * 128 + b2]; ar0.x += t.x; ar0.y += t.y;
        t = red[1 * 128 + b2]; ar1.x += t.x; ar1.y += t.y;
        t = red[2 * 128 + b2]; az0.x += t.x; az0.y += t.y;
        t = red[3 * 128 + b2]; az1.x += t.x; az1.y += t.y;
        t = red[4 * 128 + b2]; an0.x += t.x; an0.y += t.y;
        t = red[5 * 128 + b2]; an1.x += t.x; an1.y += t.y;
        float br0 = bhh[j0],        br1 = bhh[j0 + 1];
        float bz0 = bhh[512 + j0],  bz1 = bhh[513 + j0];
        float bn0 = bhh[1024 + j0], bn1 = bhh[1025 + j0];
        const float2* xp = (const float2*)xiT;
        float2 xr0 = xp[(size_t)j0 * 128 + b2],          xr1 = xp[(size_t)(j0 + 1) * 128 + b2];
        float2 xz0 = xp[(size_t)(512 + j0) * 128 + b2],  xz1 = xp[(size_t)(513 + j0) * 128 + b2];
        float2 xn0 = xp[(size_t)(1024 + j0) * 128 + b2], xn1 = xp[(size_t)(1025 + j0) * 128 + b2];
        const float2* hpp = (const float2*)hTprev;
        float2 hv0 = hpp[(size_t)j0 * 128 + b2], hv1 = hpp[(size_t)(j0 + 1) * 128 + b2];
        float2 o0, o1;
        {
            float rx = 1.f / (1.f + expf(-(xr0.x + ar0.x + br0)));
            float ry = 1.f / (1.f + expf(-(xr0.y + ar0.y + br0)));
            float zx = 1.f / (1.f + expf(-(xz0.x + az0.x + bz0)));
            float zy = 1.f / (1.f + expf(-(xz0.y + az0.y + bz0)));
            float nx = tanhf(xn0.x + rx * (an0.x + bn0));
            float ny = tanhf(xn0.y + ry * (an0.y + bn0));
            o0.x = (1.f - zx) * nx + zx * hv0.x;
            o0.y = (1.f - zy) * ny + zy * hv0.y;
        }
        {
            float rx = 1.f / (1.f + expf(-(xr1.x + ar1.x + br1)));
            float ry = 1.f / (1.f + expf(-(xr1.y + ar1.y + br1)));
            float zx = 1.f / (1.f + expf(-(xz1.x + az1.x + bz1)));
            float zy = 1.f / (1.f + expf(-(xz1.y + az1.y + bz1)));
            float nx = tanhf(xn1.x + rx * (an1.x + bn1));
            float ny = tanhf(xn1.y + ry * (an1.y + bn1));
            o1.x = (1.f - zx) * nx + zx * hv1.x;
            o1.y = (1.f - zy) * ny + zy * hv1.y;
        }
        float2* op = (float2*)hTnext;
        op[(size_t)j0 * 128 + b2] = o0;
        op[(size_t)(j0 + 1) * 128 + b2] = o1;
    }
}

// hT[512][256] -> h[256][512]
__global__ __launch_bounds__(256) void hT_to_h(
    const float* __restrict__ hT, float* __restrict__ h) {
    __shared__ float tb[64][65];
    const int tid = threadIdx.x;
    const int k0 = blockIdx.x * 64, b0 = blockIdx.y * 64;
#pragma unroll
    for (int i = 0; i < 4; ++i) {
        int r = (tid >> 4) + 16 * i;  // k row
        int c = (tid & 15) * 4;       // b col
        float4 v = *(const float4*)(hT + (size_t)(k0 + r) * 256 + b0 + c);
        tb[c + 0][r] = v.x; tb[c + 1][r] = v.y; tb[c + 2][r] = v.z; tb[c + 3][r] = v.w;
    }
    __syncthreads();
#pragma unroll
    for (int i = 0; i < 4; ++i) {
        int r = (tid >> 4) + 16 * i;  // b row
        int c = (tid & 15) * 4;       // k col
        float4 v;
        v.x = tb[r][c]; v.y = tb[r][c + 1]; v.z = tb[r][c + 2]; v.w = tb[r][c + 3];
        *(float4*)(h + (size_t)(b0 + r) * 512 + k0 + c) = v;
    }
}

__device__ __forceinline__ float blockReduceSum(float v, float* tmp) {
    __syncthreads();
#pragma unroll
    for (int o = 32; o; o >>= 1) v += __shfl_down(v, o);
    if ((threadIdx.x & 63) == 0) tmp[threadIdx.x >> 6] = v;
    __syncthreads();
    if (threadIdx.x == 0) tmp[4] = tmp[0] + tmp[1] + tmp[2] + tmp[3];
    __syncthreads();
    return tmp[4];
}

__device__ __forceinline__ float blockReduceMax(float v, float* tmp) {
    __syncthreads();
#pragma unroll
    for (int o = 32; o; o >>= 1) v = fmaxf(v, __shfl_down(v, o));
    if ((threadIdx.x & 63) == 0) tmp[threadIdx.x >> 6] = v;
    __syncthreads();
    if (threadIdx.x == 0) tmp[4] = fmaxf(fmaxf(tmp[0], tmp[1]), fmaxf(tmp[2], tmp[3]));
    __syncthreads();
    return tmp[4];
}

__global__ __launch_bounds__(256) void head_kernel(
    const float* __restrict__ h1, const float* __restrict__ fcw,
    const float* __restrict__ fcb, float* __restrict__ out) {
    __shared__ __align__(16) float hrow[512];
    __shared__ float wv[512];
    __shared__ float ov[512];
    __shared__ float tmp[8];
    const int b = blockIdx.x, tid = threadIdx.x;
    hrow[tid]       = h1[(size_t)b * 512 + tid];
    hrow[tid + 256] = h1[(size_t)b * 512 + 256 + tid];
    __syncthreads();

    float s[2];
#pragma unroll
    for (int q = 0; q < 2; ++q) {
        int n = tid + q * 256;
        const float* wr = fcw + (size_t)n * 512;
        float acc = 0.f;
        for (int k = 0; k < 512; k += 4) {
            float4 wq = *(const float4*)(wr + k);
            acc += wq.x * hrow[k] + wq.y * hrow[k + 1] + wq.z * hrow[k + 2] + wq.w * hrow[k + 3];
        }
        float l = acc + fcb[n];
        s[q] = l / (1.f + expf(-l));
    }

    float mx = blockReduceMax(fmaxf(s[0], s[1]), tmp);
    float e0 = expf(s[0] - mx), e1 = expf(s[1] - mx);
    float sum = blockReduceSum(e0 + e1, tmp);
    float w0 = e0 / sum, w1 = e1 / sum;

    ov[tid] = w0;       ov[tid + 256] = w1;
    wv[tid]       = fminf(fmaxf(w0, 0.f), 0.1f);
    wv[tid + 256] = fminf(fmaxf(w1, 0.f), 0.1f);
    __syncthreads();

    for (int it = 0; it < 32; ++it) {
        float wc0 = wv[tid], wc1 = wv[tid + 256];
        float o0 = ov[tid], o1 = ov[tid + 256];
        float leftover = blockReduceSum((o0 - wc0) + (o1 - wc1), tmp);
        float n0 = (wc0 != 0.1f) ? wc0 : 0.f;
        float n1 = (wc1 != 0.1f) ? wc1 : 0.f;
        float denom = blockReduceSum(n0 + n1, tmp);
        float w20 = wc0 + leftover * n0 / denom;
        float w21 = wc1 + leftover * n1 / denom;
        float fl = ((w20 > 0.1f) || (w21 > 0.1f)) ? 1.f : 0.f;
        bool again = blockReduceSum(fl, tmp) > 0.f;
        __syncthreads();
        ov[tid] = w20; ov[tid + 256] = w21;
        wv[tid]       = again ? fminf(fmaxf(w20, 0.f), 0.1f) : w20;
        wv[tid + 256] = again ? fminf(fmaxf(w21, 0.f), 0.1f) : w21;
        __syncthreads();
        if (!again) break;
    }

    out[(size_t)b * 512 + tid]       = wv[tid];
    out[(size_t)b * 512 + 256 + tid] = wv[tid + 256];
}

extern "C" void kernel_launch(void* const* d_in, const int* in_sizes, int n_in,
                              void* d_out, int out_size, void* d_ws, size_t ws_size,
                              hipStream_t stream) {
    const float* x    = (const float*)d_in[0];
    const float* Wih0 = (const float*)d_in[1];
    const float* Whh0 = (const float*)d_in[2];
    const float* bih0 = (const float*)d_in[3];
    const float* bhh0 = (const float*)d_in[4];
    const float* Wih1 = (const float*)d_in[5];
    const float* Whh1 = (const float*)d_in[6];
    const float* bih1 = (const float*)d_in[7];
    const float* bhh1 = (const float*)d_in[8];
    const float* fcw  = (const float*)d_in[9];
    const float* fcb  = (const float*)d_in[10];
    float* out = (float*)d_out;
    float* ws  = (float*)d_ws;

    // choose chunk size Tc from ws_size (structure correct for any Tc | 128)
    static const long tcs[6] = {32, 16, 8, 4, 2, 1};
    int Tc = 1;
    for (int i = 0; i < 6; ++i) {
        long need = (tcs[i] * (2L * XSLAB + 2L * SLAB) + 4L * SLAB) * 4L;
        if ((long)ws_size >= need) { Tc = (int)tcs[i]; break; }
    }

    float* xiT0 = ws;                              // [Tc][1536][256]
    float* xiT1 = xiT0 + (size_t)Tc * XSLAB;       // [Tc][1536][256]
    float* xT   = xiT1 + (size_t)Tc * XSLAB;       // [Tc][512][256]
    float* hT0  = xT + (size_t)Tc * SLAB;          // [Tc+1][512][256]
    float* h1a  = hT0 + (size_t)(Tc + 1) * SLAB;
    float* h1b  = h1a + SLAB;
    float* h1n  = h1b + SLAB;

    zero_kernel<<<SLAB / 256, 256, 0, stream>>>(hT0, SLAB);
    zero_kernel<<<SLAB / 256, 256, 0, stream>>>(h1a, SLAB);

    float* h1pp[2] = {h1a, h1b};
    int cur = 0;
    const int nchunks = TT / Tc;
    for (int c = 0; c < nchunks; ++c) {
        int t0 = c * Tc;
        x_transpose<<<dim3(8, 4, Tc), 256, 0, stream>>>(x, t0, xT);
        xi_gemm<<<dim3(12, Tc * 4), 256, 0, stream>>>(Wih0, bih0, xT, xiT0);
        for (int tl = 0; tl < Tc; ++tl)
            rec_step<<<256, 256, 0, stream>>>(hT0 + (size_t)tl * SLAB,
                                              xiT0 + (size_t)tl * XSLAB,
                                              Whh0, bhh0,
                                              hT0 + (size_t)(tl + 1) * SLAB);
        xi_gemm<<<dim3(12, Tc * 4), 256, 0, stream>>>(Wih1, bih1, hT0 + SLAB, xiT1);
        for (int tl = 0; tl < Tc; ++tl) {
            rec_step<<<256, 256, 0, stream>>>(h1pp[cur],
                                              xiT1 + (size_t)tl * XSLAB,
                                              Whh1, bhh1, h1pp[cur ^ 1]);
            cur ^= 1;
        }
        hipMemcpyAsync(hT0, hT0 + (size_t)Tc * SLAB, SLAB * sizeof(float),
                       hipMemcpyDeviceToDevice, stream);
    }
    hT_to_h<<<dim3(8, 4), 256, 0, stream>>>(h1pp[cur], h1n);
    head_kernel<<<BB, 256, 0, stream>>>(h1n, fcw, fcb, out);
}

// Round 3
// 2807.850 us; speedup vs baseline: 2.6955x; 1.9750x over previous
//
#include <hip/hip_runtime.h>
#include <math.h>

#define BB 256
#define TT 128
#define NN 512
#define HH 512
#define G3 1536
#define SLAB (HH * BB)     // 131072 floats: one [512][256] k-major state slab
#define XSLAB (G3 * BB)    // 393216 floats: one [1536][256] xi slab

typedef __attribute__((ext_vector_type(8))) short bf16x8;   // 8 bf16 = 4 VGPRs
typedef __attribute__((ext_vector_type(4))) float f32x4;

__device__ __forceinline__ unsigned short bf16_rne(float f) {
    union { float f; unsigned int u; } v; v.f = f;
    unsigned int r = (v.u + 0x7fffu + ((v.u >> 16) & 1u)) >> 16;
    return (unsigned short)r;
}
__device__ __forceinline__ float bf16_tof(unsigned short h) {
    union { float f; unsigned int u; } v; v.u = ((unsigned int)h) << 16;
    return v.f;
}

__global__ void zero_kernel(float* p, int n) {
    int i = blockIdx.x * blockDim.x + threadIdx.x;
    if (i < n) p[i] = 0.f;
}

// fp32 [n] -> hi/lo bf16 split
__global__ __launch_bounds__(256) void convert_split(
    const float* __restrict__ in, unsigned short* __restrict__ hi,
    unsigned short* __restrict__ lo, int n) {
    int i = (blockIdx.x * 256 + threadIdx.x) * 4;
    if (i >= n) return;
    float4 v = *(const float4*)(in + i);
    float f[4] = {v.x, v.y, v.z, v.w};
    ushort4 h, l;
    unsigned short* hp = (unsigned short*)&h;
    unsigned short* lp = (unsigned short*)&l;
#pragma unroll
    for (int q = 0; q < 4; ++q) {
        unsigned short hh = bf16_rne(f[q]);
        hp[q] = hh;
        lp[q] = bf16_rne(f[q] - bf16_tof(hh));
    }
    *(ushort4*)(hi + i) = h;
    *(ushort4*)(lo + i) = l;
}

// x[b][t0+t][k] -> Xh/Xl [t][b][k] bf16 split (b-major, natural row copy)
__global__ __launch_bounds__(128) void x_to_bf16(
    const float* __restrict__ x, int t0,
    unsigned short* __restrict__ Xh, unsigned short* __restrict__ Xl) {
    const int t = blockIdx.x, b = blockIdx.y;
    const int k = threadIdx.x * 4;
    float4 v = *(const float4*)(x + ((size_t)b * TT + (t0 + t)) * NN + k);
    float f[4] = {v.x, v.y, v.z, v.w};
    ushort4 h, l;
    unsigned short* hp = (unsigned short*)&h;
    unsigned short* lp = (unsigned short*)&l;
#pragma unroll
    for (int q = 0; q < 4; ++q) {
        unsigned short hh = bf16_rne(f[q]);
        hp[q] = hh;
        lp[q] = bf16_rne(f[q] - bf16_tof(hh));
    }
    size_t d = ((size_t)t * 256 + b) * 512 + k;
    *(ushort4*)(Xh + d) = h;
    *(ushort4*)(Xl + d) = l;
}

// hT slabs [1+t][512 k][256 b] fp32 -> Hh/Hl [t][256 b][512 k] bf16 (transpose+split)
__global__ __launch_bounds__(256) void hT_to_bf16(
    const float* __restrict__ hTbase,
    unsigned short* __restrict__ Hh, unsigned short* __restrict__ Hl) {
    __shared__ float tb[64][65];
    const int tid = threadIdx.x;
    const int k0 = blockIdx.x * 64, b0 = blockIdx.y * 64, t = blockIdx.z;
    const float* src = hTbase + (size_t)(t + 1) * SLAB;
#pragma unroll
    for (int i = 0; i < 4; ++i) {
        int r = (tid >> 4) + 16 * i;      // k row
        int c = (tid & 15) * 4;           // b col
        float4 v = *(const float4*)(src + (size_t)(k0 + r) * 256 + b0 + c);
        tb[c + 0][r] = v.x; tb[c + 1][r] = v.y; tb[c + 2][r] = v.z; tb[c + 3][r] = v.w;
    }
    __syncthreads();
#pragma unroll
    for (int i = 0; i < 4; ++i) {
        int r = (tid >> 4) + 16 * i;      // b row
        int c = (tid & 15) * 4;           // k col
        float f[4] = {tb[r][c], tb[r][c + 1], tb[r][c + 2], tb[r][c + 3]};
        ushort4 h, l;
        unsigned short* hp = (unsigned short*)&h;
        unsigned short* lp = (unsigned short*)&l;
#pragma unroll
        for (int q = 0; q < 4; ++q) {
            unsigned short hh = bf16_rne(f[q]);
            hp[q] = hh;
            lp[q] = bf16_rne(f[q] - bf16_tof(hh));
        }
        size_t d = ((size_t)t * 256 + b0 + r) * 512 + k0 + c;
        *(ushort4*)(Hh + d) = h;
        *(ushort4*)(Hl + d) = l;
    }
}

// xi[t][g][b] = sum_k W[g][k]*X[t][b][k] + bias[g], split-bf16 MFMA (3 terms)
// block: 128g x 128b tile, 4 waves (2x2), wave = 64x64 via 4x4 16x16x32 frags
__global__ __launch_bounds__(256) void xi_mfma(
    const unsigned short* __restrict__ Whi, const unsigned short* __restrict__ Wlo,
    const unsigned short* __restrict__ Xhi, const unsigned short* __restrict__ Xlo,
    const float* __restrict__ bias, float* __restrict__ out) {
    __shared__ unsigned short As[2][128][40];
    __shared__ unsigned short Bs[2][128][40];
    const int tid = threadIdx.x;
    const int g0 = blockIdx.x * 128;
    const int b0 = blockIdx.y * 128;
    const int t  = blockIdx.z;
    const unsigned short* Xh = Xhi + (size_t)t * (256 * 512);
    const unsigned short* Xl = Xlo + (size_t)t * (256 * 512);

    const int w = tid >> 6, lane = tid & 63;
    const int wg = (w >> 1) * 64, wb = (w & 1) * 64;
    const int l15 = lane & 15, l4 = lane >> 4;

    f32x4 acc[4][4] = {};

    const int sr = tid >> 2;          // 0..63 staging row
    const int sc = (tid & 3) * 8;     // k element offset (0,8,16,24)

    for (int kc = 0; kc < 512; kc += 32) {
        uint4 a0 = *(const uint4*)(Whi + (size_t)(g0 + sr) * 512 + kc + sc);
        uint4 a1 = *(const uint4*)(Whi + (size_t)(g0 + 64 + sr) * 512 + kc + sc);
        uint4 a2 = *(const uint4*)(Wlo + (size_t)(g0 + sr) * 512 + kc + sc);
        uint4 a3 = *(const uint4*)(Wlo + (size_t)(g0 + 64 + sr) * 512 + kc + sc);
        uint4 b0v = *(const uint4*)(Xh + (size_t)(b0 + sr) * 512 + kc + sc);
        uint4 b1v = *(const uint4*)(Xh + (size_t)(b0 + 64 + sr) * 512 + kc + sc);
        uint4 b2v = *(const uint4*)(Xl + (size_t)(b0 + sr) * 512 + kc + sc);
        uint4 b3v = *(const uint4*)(Xl + (size_t)(b0 + 64 + sr) * 512 + kc + sc);
        __syncthreads();   // prior frag reads complete before overwrite
        *(uint4*)&As[0][sr][sc] = a0;      *(uint4*)&As[0][64 + sr][sc] = a1;
        *(uint4*)&As[1][sr][sc] = a2;      *(uint4*)&As[1][64 + sr][sc] = a3;
        *(uint4*)&Bs[0][sr][sc] = b0v;     *(uint4*)&Bs[0][64 + sr][sc] = b1v;
        *(uint4*)&Bs[1][sr][sc] = b2v;     *(uint4*)&Bs[1][64 + sr][sc] = b3v;
        __syncthreads();
        bf16x8 ah[4], al[4], bh[4], bl[4];
#pragma unroll
        for (int i = 0; i < 4; ++i) {
            ah[i] = *(const bf16x8*)&As[0][wg + 16 * i + l15][l4 * 8];
            al[i] = *(const bf16x8*)&As[1][wg + 16 * i + l15][l4 * 8];
            bh[i] = *(const bf16x8*)&Bs[0][wb + 16 * i + l15][l4 * 8];
            bl[i] = *(const bf16x8*)&Bs[1][wb + 16 * i + l15][l4 * 8];
        }
#pragma unroll
        for (int i = 0; i < 4; ++i)
#pragma unroll
            for (int j = 0; j < 4; ++j) {
                acc[i][j] = __builtin_amdgcn_mfma_f32_16x16x32_bf16(ah[i], bh[j], acc[i][j], 0, 0, 0);
                acc[i][j] = __builtin_amdgcn_mfma_f32_16x16x32_bf16(ah[i], bl[j], acc[i][j], 0, 0, 0);
                acc[i][j] = __builtin_amdgcn_mfma_f32_16x16x32_bf16(al[i], bh[j], acc[i][j], 0, 0, 0);
            }
    }
    float* op = out + (size_t)t * XSLAB;
#pragma unroll
    for (int i = 0; i < 4; ++i) {
        int gbase = g0 + wg + 16 * i + l4 * 4;
#pragma unroll
        for (int r = 0; r < 4; ++r) {
            float bv = bias[gbase + r];
#pragma unroll
            for (int j = 0; j < 4; ++j)
                op[(size_t)(gbase + r) * 256 + b0 + wb + 16 * j + l15] = acc[i][j][r] + bv;
        }
    }
}

__device__ __forceinline__ float gru1(float xr, float hr, float xz, float hz,
                                      float xn, float hn, float h) {
    float r = 1.f / (1.f + expf(-(xr + hr)));
    float z = 1.f / (1.f + expf(-(xz + hz)));
    float n = tanhf(xn + r * hn);
    return (1.f - z) * n + z * h;
}

// Fused recurrent step: gh = h@Whh^T + bhh (SGPR-weight dot), gates, h-update.
// 256 blocks (2 j-cols each) x 512 threads (64 b-quads x 8 k-eighths).
__global__ __launch_bounds__(512) void rec_step(
    const float* __restrict__ hTprev,   // [512][256]
    const float* __restrict__ xiT,      // [1536][256] this t
    const float* __restrict__ Whh,      // [1536][512]
    const float* __restrict__ bhh,      // [1536]
    float* __restrict__ hTnext) {       // [512][256]
    __shared__ f32x4 red[7][64][6];
    const int tid = threadIdx.x;
    const int b4 = tid & 63;
    const int kq = __builtin_amdgcn_readfirstlane(tid >> 6);  // 0..7 wave-uniform
    const int j0 = blockIdx.x * 2;
    const float* wr0 = Whh + (size_t)(j0)*512 + kq * 64;
    const float* wr1 = Whh + (size_t)(j0 + 1) * 512 + kq * 64;
    const float* wz0 = Whh + (size_t)(512 + j0) * 512 + kq * 64;
    const float* wz1 = Whh + (size_t)(513 + j0) * 512 + kq * 64;
    const float* wn0 = Whh + (size_t)(1024 + j0) * 512 + kq * 64;
    const float* wn1 = Whh + (size_t)(1025 + j0) * 512 + kq * 64;
    const float4* hp = (const float4*)hTprev + (size_t)kq * 64 * 64 + b4;

    float4 ar0 = {0, 0, 0, 0}, ar1 = ar0, az0 = ar0, az1 = ar0, an0 = ar0, an1 = ar0;
#pragma unroll 8
    for (int k = 0; k < 64; ++k) {
        float4 hv = hp[(size_t)k * 64];
        float q;
        q = wr0[k]; ar0.x += q * hv.x; ar0.y += q * hv.y; ar0.z += q * hv.z; ar0.w += q * hv.w;
        q = wr1[k]; ar1.x += q * hv.x; ar1.y += q * hv.y; ar1.z += q * hv.z; ar1.w += q * hv.w;
        q = wz0[k]; az0.x += q * hv.x; az0.y += q * hv.y; az0.z += q * hv.z; az0.w += q * hv.w;
        q = wz1[k]; az1.x += q * hv.x; az1.y += q * hv.y; az1.z += q * hv.z; az1.w += q * hv.w;
        q = wn0[k]; an0.x += q * hv.x; an0.y += q * hv.y; an0.z += q * hv.z; an0.w += q * hv.w;
        q = wn1[k]; an1.x += q * hv.x; an1.y += q * hv.y; an1.z += q * hv.z; an1.w += q * hv.w;
    }
    if (kq) {
        f32x4* rp = &red[kq - 1][b4][0];
        rp[0] = f32x4{ar0.x, ar0.y, ar0.z, ar0.w};
        rp[1] = f32x4{ar1.x, ar1.y, ar1.z, ar1.w};
        rp[2] = f32x4{az0.x, az0.y, az0.z, az0.w};
        rp[3] = f32x4{az1.x, az1.y, az1.z, az1.w};
        rp[4] = f32x4{an0.x, an0.y, an0.z, an0.w};
        rp[5] = f32x4{an1.x, an1.y, an1.z, an1.w};
    }
    __syncthreads();
    if (kq == 0) {
#pragma unroll
        for (int p = 0; p < 7; ++p) {
            const f32x4* rp = &red[p][b4][0];
            f32x4 v;
            v = rp[0]; ar0.x += v[0]; ar0.y += v[1]; ar0.z += v[2]; ar0.w += v[3];
            v = rp[1]; ar1.x += v[0]; ar1.y += v[1]; ar1.z += v[2]; ar1.w += v[3];
            v = rp[2]; az0.x += v[0]; az0.y += v[1]; az0.z += v[2]; az0.w += v[3];
            v = rp[3]; az1.x += v[0]; az1.y += v[1]; az1.z += v[2]; az1.w += v[3];
            v = rp[4]; an0.x += v[0]; an0.y += v[1]; an0.z += v[2]; an0.w += v[3];
            v = rp[5]; an1.x += v[0]; an1.y += v[1]; an1.z += v[2]; an1.w += v[3];
        }
        const float4* xi4 = (const float4*)xiT;
        const float4* h4 = (const float4*)hTprev;
        float4 xr0 = xi4[(size_t)(j0)*64 + b4],        xr1 = xi4[(size_t)(j0 + 1) * 64 + b4];
        float4 xz0 = xi4[(size_t)(512 + j0) * 64 + b4], xz1 = xi4[(size_t)(513 + j0) * 64 + b4];
        float4 xn0 = xi4[(size_t)(1024 + j0) * 64 + b4], xn1 = xi4[(size_t)(1025 + j0) * 64 + b4];
        float4 hv0 = h4[(size_t)j0 * 64 + b4],          hv1 = h4[(size_t)(j0 + 1) * 64 + b4];
        float br0 = bhh[j0], br1 = bhh[j0 + 1];
        float bz0 = bhh[512 + j0], bz1 = bhh[513 + j0];
        float bn0 = bhh[1024 + j0], bn1 = bhh[1025 + j0];
        float4 o0, o1;
        o0.x = gru1(xr0.x, ar0.x + br0, xz0.x, az0.x + bz0, xn0.x, an0.x + bn0, hv0.x);
        o0.y = gru1(xr0.y, ar0.y + br0, xz0.y, az0.y + bz0, xn0.y, an0.y + bn0, hv0.y);
        o0.z = gru1(xr0.z, ar0.z + br0, xz0.z, az0.z + bz0, xn0.z, an0.z + bn0, hv0.z);
        o0.w = gru1(xr0.w, ar0.w + br0, xz0.w, az0.w + bz0, xn0.w, an0.w + bn0, hv0.w);
        o1.x = gru1(xr1.x, ar1.x + br1, xz1.x, az1.x + bz1, xn1.x, an1.x + bn1, hv1.x);
        o1.y = gru1(xr1.y, ar1.y + br1, xz1.y, az1.y + bz1, xn1.y, an1.y + bn1, hv1.y);
        o1.z = gru1(xr1.z, ar1.z + br1, xz1.z, az1.z + bz1, xn1.z, an1.z + bn1, hv1.z);
        o1.w = gru1(xr1.w, ar1.w + br1, xz1.w, az1.w + bz1, xn1.w, an1.w + bn1, hv1.w);
        ((float4*)hTnext)[(size_t)j0 * 64 + b4] = o0;
        ((float4*)hTnext)[(size_t)(j0 + 1) * 64 + b4] = o1;
    }
}

// hT[512][256] -> h[256][512]
__global__ __launch_bounds__(256) void hT_to_h(
    const float* __restrict__ hT, float* __restrict__ h) {
    __shared__ float tb[64][65];
    const int tid = threadIdx.x;
    const int k0 = blockIdx.x * 64, b0 = blockIdx.y * 64;
#pragma unroll
    for (int i = 0; i < 4; ++i) {
        int r = (tid >> 4) + 16 * i;
        int c = (tid & 15) * 4;
        float4 v = *(const float4*)(hT + (size_t)(k0 + r) * 256 + b0 + c);
        tb[c + 0][r] = v.x; tb[c + 1][r] = v.y; tb[c + 2][r] = v.z; tb[c + 3][r] = v.w;
    }
    __syncthreads();
#pragma unroll
    for (int i = 0; i < 4; ++i) {
        int r = (tid >> 4) + 16 * i;
        int c = (tid & 15) * 4;
        float4 v;
        v.x = tb[r][c]; v.y = tb[r][c + 1]; v.z = tb[r][c + 2]; v.w = tb[r][c + 3];
        *(float4*)(h + (size_t)(b0 + r) * 512 + k0 + c) = v;
    }
}

__device__ __forceinline__ float blockReduceSum(float v, float* tmp) {
    __syncthreads();
#pragma unroll
    for (int o = 32; o; o >>= 1) v += __shfl_down(v, o);
    if ((threadIdx.x & 63) == 0) tmp[threadIdx.x >> 6] = v;
    __syncthreads();
    if (threadIdx.x == 0) tmp[4] = tmp[0] + tmp[1] + tmp[2] + tmp[3];
    __syncthreads();
    return tmp[4];
}

__device__ __forceinline__ float blockReduceMax(float v, float* tmp) {
    __syncthreads();
#pragma unroll
    for (int o = 32; o; o >>= 1) v = fmaxf(v, __shfl_down(v, o));
    if ((threadIdx.x & 63) == 0) tmp[threadIdx.x >> 6] = v;
    __syncthreads();
    if (threadIdx.x == 0) tmp[4] = fmaxf(fmaxf(tmp[0], tmp[1]), fmaxf(tmp[2], tmp[3]));
    __syncthreads();
    return tmp[4];
}

__global__ __launch_bounds__(256) void head_kernel(
    const float* __restrict__ h1, const float* __restrict__ fcw,
    const float* __restrict__ fcb, float* __restrict__ out) {
    __shared__ __align__(16) float hrow[512];
    __shared__ float wv[512];
    __shared__ float ov[512];
    __shared__ float tmp[8];
    const int b = blockIdx.x, tid = threadIdx.x;
    hrow[tid]       = h1[(size_t)b * 512 + tid];
    hrow[tid + 256] = h1[(size_t)b * 512 + 256 + tid];
    __syncthreads();

    float s[2];
#pragma unroll
    for (int q = 0; q < 2; ++q) {
        int n = tid + q * 256;
        const float* wr = fcw + (size_t)n * 512;
        float acc = 0.f;
        for (int k = 0; k < 512; k += 4) {
            float4 wq = *(const float4*)(wr + k);
            acc += wq.x * hrow[k] + wq.y * hrow[k + 1] + wq.z * hrow[k + 2] + wq.w * hrow[k + 3];
        }
        float l = acc + fcb[n];
        s[q] = l / (1.f + expf(-l));
    }

    float mx = blockReduceMax(fmaxf(s[0], s[1]), tmp);
    float e0 = expf(s[0] - mx), e1 = expf(s[1] - mx);
    float sum = blockReduceSum(e0 + e1, tmp);
    float w0 = e0 / sum, w1 = e1 / sum;

    ov[tid] = w0;       ov[tid + 256] = w1;
    wv[tid]       = fminf(fmaxf(w0, 0.f), 0.1f);
    wv[tid + 256] = fminf(fmaxf(w1, 0.f), 0.1f);
    __syncthreads();

    for (int it = 0; it < 32; ++it) {
        float wc0 = wv[tid], wc1 = wv[tid + 256];
        float o0 = ov[tid], o1 = ov[tid + 256];
        float leftover = blockReduceSum((o0 - wc0) + (o1 - wc1), tmp);
        float n0 = (wc0 != 0.1f) ? wc0 : 0.f;
        float n1 = (wc1 != 0.1f) ? wc1 : 0.f;
        float denom = blockReduceSum(n0 + n1, tmp);
        float w20 = wc0 + leftover * n0 / denom;
        float w21 = wc1 + leftover * n1 / denom;
        float fl = ((w20 > 0.1f) || (w21 > 0.1f)) ? 1.f : 0.f;
        bool again = blockReduceSum(fl, tmp) > 0.f;
        __syncthreads();
        ov[tid] = w20; ov[tid + 256] = w21;
        wv[tid]       = again ? fminf(fmaxf(w20, 0.f), 0.1f) : w20;
        wv[tid + 256] = again ? fminf(fmaxf(w21, 0.f), 0.1f) : w21;
        __syncthreads();
        if (!again) break;
    }

    out[(size_t)b * 512 + tid]       = wv[tid];
    out[(size_t)b * 512 + 256 + tid] = wv[tid + 256];
}

extern "C" void kernel_launch(void* const* d_in, const int* in_sizes, int n_in,
                              void* d_out, int out_size, void* d_ws, size_t ws_size,
                              hipStream_t stream) {
    const float* x    = (const float*)d_in[0];
    const float* Wih0 = (const float*)d_in[1];
    const float* Whh0 = (const float*)d_in[2];
    const float* bih0 = (const float*)d_in[3];
    const float* bhh0 = (const float*)d_in[4];
    const float* Wih1 = (const float*)d_in[5];
    const float* Whh1 = (const float*)d_in[6];
    const float* bih1 = (const float*)d_in[7];
    const float* bhh1 = (const float*)d_in[8];
    const float* fcw  = (const float*)d_in[9];
    const float* fcb  = (const float*)d_in[10];
    float* out = (float*)d_out;
    float* ws  = (float*)d_ws;

    // Tc selection: floats = Tc*(XSLAB + 2*SLAB) + 4*SLAB + 4*(G3*HH)/2
    static const long tcs[6] = {32, 16, 8, 4, 2, 1};
    int Tc = 1;
    for (int i = 0; i < 6; ++i) {
        long need = (tcs[i] * ((long)XSLAB + 2L * SLAB) + 4L * SLAB + 2L * G3 * HH) * 4L;
        if ((long)ws_size >= need) { Tc = (int)tcs[i]; break; }
    }

    float* xi  = ws;                                // [Tc][XSLAB]
    float* hT0 = xi + (size_t)Tc * XSLAB;           // [Tc+1][SLAB]
    float* h1a = hT0 + (size_t)(Tc + 1) * SLAB;
    float* h1b = h1a + SLAB;
    float* h1n = h1b + SLAB;
    unsigned short* Xh = (unsigned short*)(h1n + SLAB);          // [Tc][256][512]
    unsigned short* Xl = Xh + (size_t)Tc * 256 * 512;
    unsigned short* W0h = Xl + (size_t)Tc * 256 * 512;           // [1536][512] x4
    unsigned short* W0l = W0h + (size_t)G3 * HH;
    unsigned short* W1h = W0l + (size_t)G3 * HH;
    unsigned short* W1l = W1h + (size_t)G3 * HH;

    const int wn = G3 * HH;   // 786432
    convert_split<<<wn / 1024, 256, 0, stream>>>(Wih0, W0h, W0l, wn);
    convert_split<<<wn / 1024, 256, 0, stream>>>(Wih1, W1h, W1l, wn);
    zero_kernel<<<SLAB / 256, 256, 0, stream>>>(hT0, SLAB);
    zero_kernel<<<SLAB / 256, 256, 0, stream>>>(h1a, SLAB);

    float* h1pp[2] = {h1a, h1b};
    int cur = 0;
    const int nchunks = TT / Tc;
    for (int c = 0; c < nchunks; ++c) {
        int t0 = c * Tc;
        x_to_bf16<<<dim3(Tc, 256), 128, 0, stream>>>(x, t0, Xh, Xl);
        xi_mfma<<<dim3(12, 2, Tc), 256, 0, stream>>>(W0h, W0l, Xh, Xl, bih0, xi);
        for (int tl = 0; tl < Tc; ++tl)
            rec_step<<<256, 512, 0, stream>>>(hT0 + (size_t)tl * SLAB,
                                              xi + (size_t)tl * XSLAB,
                                              Whh0, bhh0,
                                              hT0 + (size_t)(tl + 1) * SLAB);
        hT_to_bf16<<<dim3(8, 4, Tc), 256, 0, stream>>>(hT0, Xh, Xl);
        xi_mfma<<<dim3(12, 2, Tc), 256, 0, stream>>>(W1h, W1l, Xh, Xl, bih1, xi);
        for (int tl = 0; tl < Tc; ++tl) {
            rec_step<<<256, 512, 0, stream>>>(h1pp[cur],
                                              xi + (size_t)tl * XSLAB,
                                              Whh1, bhh1, h1pp[cur ^ 1]);
            cur ^= 1;
        }
        hipMemcpyAsync(hT0, hT0 + (size_t)Tc * SLAB, SLAB * sizeof(float),
                       hipMemcpyDeviceToDevice, stream);
    }
    hT_to_h<<<dim3(8, 4), 256, 0, stream>>>(h1pp[cur], h1n);
    head_kernel<<<BB, 256, 0, stream>>>(h1n, fcw, fcb, out);
}